// Round 12
// baseline (73.410 us; speedup 1.0000x reference)
//
#include <hip/hip_runtime.h>

#define D256 256
#define KT 8
#define S_SEQ 1024
#define OUTSEQ 512

typedef __attribute__((ext_vector_type(8))) short bf16x8;
typedef __attribute__((ext_vector_type(8))) unsigned short u16x8;
typedef __attribute__((ext_vector_type(4))) unsigned short u16x4;
typedef __attribute__((ext_vector_type(4))) float f32x4;

__device__ inline unsigned short f2bf(float f) {          // RNE fp32->bf16
  unsigned u = __float_as_uint(f);
  return (unsigned short)((u + 0x7fffu + ((u >> 16) & 1u)) >> 16);
}

// ---------------- prep ----------------
// blocks   0..255 : PIt4[j][i] = {P[i][j], 1/p, cb2, 0}, p = i*256+j+2
// blocks 256..511 : LinkTb[t][s] = bf16( s<1024 ? Linker[s][t] : rLinker[s-1024][t] )
// blocks 512..767 : xb  = bf16(x)      (flat convert, 2048 elems/block)
// blocks 768..799 : Mb  = bf16(M)      (flat)
// blocks 800..831 : Wb  = bf16(res_W)  (flat)
__global__ __launch_bounds__(256) void k_prep(const float* __restrict__ x,
                                              const float* __restrict__ M,
                                              const float* __restrict__ resW,
                                              const float* __restrict__ P,
                                              const float* __restrict__ Linker,
                                              const float* __restrict__ rLinker,
                                              float4* __restrict__ PIt4,
                                              unsigned short* __restrict__ LinkTb,
                                              unsigned short* __restrict__ xb,
                                              unsigned short* __restrict__ Mb,
                                              unsigned short* __restrict__ Wb) {
  __shared__ float tl[64][65];
  const int tid = threadIdx.x;
  const int blk = blockIdx.x;
  if (blk < 256) {
    const int j = blk;
    const int t = tid;
    const float p = (float)(t * D256 + j + 2);
    const float ip = 1.0f / p;
    const float cb2 = 2.0f * __builtin_amdgcn_cosf(ip);   // v_cos takes revolutions
    PIt4[j * D256 + t] = make_float4(P[t * D256 + j], ip, cb2, 0.0f);
    return;
  }
  if (blk >= 512) {                     // flat fp32 -> bf16 converts
    const float* src;
    unsigned short* dst;
    size_t base;
    if (blk < 768)      { src = x;    dst = xb; base = (size_t)(blk - 512) * 2048; }
    else if (blk < 800) { src = M;    dst = Mb; base = (size_t)(blk - 768) * 2048; }
    else                { src = resW; dst = Wb; base = (size_t)(blk - 800) * 2048; }
    const size_t off = base + (size_t)tid * 8;
    const float4 v0 = *(const float4*)(src + off);
    const float4 v1 = *(const float4*)(src + off + 4);
    u16x8 o;
    o[0] = f2bf(v0.x); o[1] = f2bf(v0.y); o[2] = f2bf(v0.z); o[3] = f2bf(v0.w);
    o[4] = f2bf(v1.x); o[5] = f2bf(v1.y); o[6] = f2bf(v1.z); o[7] = f2bf(v1.w);
    *(u16x8*)(dst + off) = o;
    return;
  }
  // LinkTb transpose-pack
  const int tb = blk - 256;             // 0..255
  const int st = tb & 31;               // s-tile (64 rows)
  const int tt = tb >> 5;               // t-tile (64 cols)
  const int s0 = st * 64, t0 = tt * 64;
  const float* src = (s0 < 1024) ? (Linker + (size_t)s0 * OUTSEQ)
                                 : (rLinker + (size_t)(s0 - 1024) * OUTSEQ);
  {
    const int sy = tid >> 2, sx = tid & 3;
    #pragma unroll
    for (int c = 0; c < 4; ++c) {
      const int ci = sx + c * 4;
      const float4 v = *(const float4*)&src[sy * OUTSEQ + t0 + ci * 4];
      tl[ci * 4 + 0][sy] = v.x;
      tl[ci * 4 + 1][sy] = v.y;
      tl[ci * 4 + 2][sy] = v.z;
      tl[ci * 4 + 3][sy] = v.w;
    }
  }
  __syncthreads();
  {
    const int ty = tid >> 2, tx = tid & 3;
    u16x8 o0, o1;
    #pragma unroll
    for (int e = 0; e < 8; ++e) o0[e] = f2bf(tl[ty][tx * 16 + e]);
    #pragma unroll
    for (int e = 0; e < 8; ++e) o1[e] = f2bf(tl[ty][tx * 16 + 8 + e]);
    unsigned short* dst = LinkTb + (size_t)(t0 + ty) * 2048 + s0 + tx * 16;
    *(u16x8*)dst = o0;
    *(u16x8*)(dst + 8) = o1;
  }
}

// ---------------- k_Azn: MFMA phase A + LN ----------------
__global__ __launch_bounds__(256) void k_Azn(const unsigned short* __restrict__ xb,
                                             const unsigned short* __restrict__ Mb,
                                             const unsigned short* __restrict__ Wb,
                                             const float* __restrict__ gamma,
                                             const float* __restrict__ beta,
                                             float* __restrict__ Zb,
                                             unsigned short* __restrict__ Bt) {
  __shared__ float Zs[16][D256];
  __shared__ float Rs[16][D256];
  __shared__ float mu_s[16], rs_s[16];
  const int k0 = blockIdx.x * 16;
  const int w = threadIdx.x >> 6;
  const int l = threadIdx.x & 63;
  const int m = l & 15, q = l >> 4;

  f32x4 aZ[4] = {}, aR[4] = {};
  const unsigned short* Arow = xb + (size_t)(k0 + m) * D256;
  #pragma unroll
  for (int ks = 0; ks < 8; ++ks) {
    const bf16x8 a = *(const bf16x8*)(Arow + ks * 32 + q * 8);
    #pragma unroll
    for (int cf = 0; cf < 4; ++cf) {
      const int o = w * 64 + cf * 16 + m;
      const bf16x8 bz = *(const bf16x8*)(Mb + (size_t)o * D256 + ks * 32 + q * 8);
      const bf16x8 br = *(const bf16x8*)(Wb + (size_t)o * D256 + ks * 32 + q * 8);
      aZ[cf] = __builtin_amdgcn_mfma_f32_16x16x32_bf16(a, bz, aZ[cf], 0, 0, 0);
      aR[cf] = __builtin_amdgcn_mfma_f32_16x16x32_bf16(a, br, aR[cf], 0, 0, 0);
    }
  }
  #pragma unroll
  for (int cf = 0; cf < 4; ++cf) {
    #pragma unroll
    for (int r = 0; r < 4; ++r) {
      Zs[q * 4 + r][w * 64 + cf * 16 + m] = aZ[cf][r];
      Rs[q * 4 + r][w * 64 + cf * 16 + m] = aR[cf][r];
    }
  }
  __syncthreads();

  #pragma unroll
  for (int rr = w; rr < 16; rr += 4) {
    float s = 0.f, sq = 0.f;
    #pragma unroll
    for (int p = 0; p < 4; ++p) {
      const float v = Zs[rr][l + 64 * p];
      s += v;
      sq = fmaf(v, v, sq);
    }
    #pragma unroll
    for (int off = 32; off; off >>= 1) {
      s += __shfl_down(s, off);
      sq += __shfl_down(sq, off);
    }
    if (l == 0) {
      const float mu = s * (1.0f / 256.0f);
      const float var = sq * (1.0f / 256.0f) - mu * mu;
      mu_s[rr] = mu;
      rs_s[rr] = rsqrtf(var + 1e-5f);
    }
  }
  __syncthreads();

  {
    const int t = threadIdx.x;
    const float g = gamma[t], be = beta[t];
    u16x8 o0, o1;
    #pragma unroll
    for (int rr = 0; rr < 16; ++rr) {
      Zb[(size_t)(k0 + rr) * D256 + t] = (Zs[rr][t] - mu_s[rr]) * rs_s[rr] * g + be;
      const unsigned short rb = f2bf(Rs[rr][t]);
      if (rr < 8) o0[rr] = rb; else o1[rr - 8] = rb;
    }
    unsigned short* dst = Bt + (size_t)t * 4096 + 2048 + k0;
    *(u16x8*)dst = o0;
    *(u16x8*)(dst + 8) = o1;
  }
}

// ---------------- k_B: cos-einsum, 16-long Chebyshev chains ----------------
// DIAGNOSTIC: main loop repeated 4x (opaque jr defeats CSE; asm keeps reps live).
// Result identical to 1x; dur ~= stage + 4*main + tail.
__global__ __launch_bounds__(256, 6) void k_B(const float* __restrict__ Zb,
                                              const float4* __restrict__ PIt4,
                                              unsigned short* __restrict__ Bt) {
  __shared__ float buf[5120];           // 20 KB
  const int tid = threadIdx.x;
  const int il = tid & 7;
  const int jg = tid >> 3;              // 0..31
  const int ig = blockIdx.x & 31;
  const int kt = blockIdx.x >> 5;
  const int i0 = ig * 8;
  const int k0 = kt * 16;
  const int i  = i0 + il;

  #pragma unroll
  for (int r = 0; r < 16; ++r)
    buf[tid * 20 + r] = Zb[(size_t)(k0 + r) * D256 + tid];
  __syncthreads();

  float acc[16];
  const float kf0 = (float)k0;
  const float4* pip = PIt4 + i;

  #pragma unroll 1
  for (int rep = 0; rep < 4; ++rep) {
    int jr = 0;
    asm volatile("" : "+v"(jr));        // opaque zero: forces per-rep re-execution
    #pragma unroll
    for (int k = 0; k < 16; ++k) acc[k] = 0.f;
    #pragma unroll
    for (int jj = 0; jj < 8; ++jj) {
      const int j = jg + 32 * jj + jr;
      const float4 pi = pip[(size_t)j * D256];       // {P, 1/p, cb2, 0}
      const float4 z0 = *(const float4*)&buf[j * 20 + 0];
      const float4 z1 = *(const float4*)&buf[j * 20 + 4];
      const float4 z2 = *(const float4*)&buf[j * 20 + 8];
      const float4 z3 = *(const float4*)&buf[j * 20 + 12];
      const float a = kf0 * pi.y;
      float c0 = __builtin_amdgcn_cosf(__builtin_amdgcn_fractf(a)) * pi.x;
      float c1 = __builtin_amdgcn_cosf(__builtin_amdgcn_fractf(a + pi.y)) * pi.x;
      acc[0] = fmaf(z0.x, c0, acc[0]);
      acc[1] = fmaf(z0.y, c1, acc[1]);
      float c2;
      c2 = fmaf(pi.z, c1, -c0); acc[2]  = fmaf(z0.z, c2, acc[2]);  c0 = c1; c1 = c2;
      c2 = fmaf(pi.z, c1, -c0); acc[3]  = fmaf(z0.w, c2, acc[3]);  c0 = c1; c1 = c2;
      c2 = fmaf(pi.z, c1, -c0); acc[4]  = fmaf(z1.x, c2, acc[4]);  c0 = c1; c1 = c2;
      c2 = fmaf(pi.z, c1, -c0); acc[5]  = fmaf(z1.y, c2, acc[5]);  c0 = c1; c1 = c2;
      c2 = fmaf(pi.z, c1, -c0); acc[6]  = fmaf(z1.z, c2, acc[6]);  c0 = c1; c1 = c2;
      c2 = fmaf(pi.z, c1, -c0); acc[7]  = fmaf(z1.w, c2, acc[7]);  c0 = c1; c1 = c2;
      c2 = fmaf(pi.z, c1, -c0); acc[8]  = fmaf(z2.x, c2, acc[8]);  c0 = c1; c1 = c2;
      c2 = fmaf(pi.z, c1, -c0); acc[9]  = fmaf(z2.y, c2, acc[9]);  c0 = c1; c1 = c2;
      c2 = fmaf(pi.z, c1, -c0); acc[10] = fmaf(z2.z, c2, acc[10]); c0 = c1; c1 = c2;
      c2 = fmaf(pi.z, c1, -c0); acc[11] = fmaf(z2.w, c2, acc[11]); c0 = c1; c1 = c2;
      c2 = fmaf(pi.z, c1, -c0); acc[12] = fmaf(z3.x, c2, acc[12]); c0 = c1; c1 = c2;
      c2 = fmaf(pi.z, c1, -c0); acc[13] = fmaf(z3.y, c2, acc[13]); c0 = c1; c1 = c2;
      c2 = fmaf(pi.z, c1, -c0); acc[14] = fmaf(z3.z, c2, acc[14]); c0 = c1; c1 = c2;
      c2 = fmaf(pi.z, c1, -c0); acc[15] = fmaf(z3.w, c2, acc[15]);
    }
    if (rep != 3) {
      asm volatile("" ::
        "v"(acc[0]), "v"(acc[1]), "v"(acc[2]), "v"(acc[3]),
        "v"(acc[4]), "v"(acc[5]), "v"(acc[6]), "v"(acc[7]),
        "v"(acc[8]), "v"(acc[9]), "v"(acc[10]), "v"(acc[11]),
        "v"(acc[12]), "v"(acc[13]), "v"(acc[14]), "v"(acc[15]));
    }
  }
  __syncthreads();

  #pragma unroll
  for (int k = 0; k < 16; ++k)
    buf[jg * 132 + k * 8 + il] = acc[k];
  __syncthreads();

  float tv = 0.f;
  if (tid < 128) {
    #pragma unroll
    for (int g = 0; g < 32; ++g) tv += buf[g * 132 + tid];
  }
  __syncthreads();
  if (tid < 128) buf[(tid & 7) * 16 + (tid >> 3)] = tv;
  __syncthreads();
  if (tid < 32) {
    const int iw = tid >> 2;
    const int kq = tid & 3;
    const float4 v = *(const float4*)&buf[iw * 16 + kq * 4];
    u16x4 o;
    o[0] = f2bf(v.x); o[1] = f2bf(v.y); o[2] = f2bf(v.z); o[3] = f2bf(v.w);
    *(u16x4*)(Bt + (size_t)(i0 + iw) * 4096 + k0 + kq * 4) = o;
  }
}

// ---------------- k_Cm: bf16 MFMA GEMM, direct out, 512 blocks ----------------
// grid 512 = b(2) x tt(32: 16-row tiles) x ct(8); 4 waves = (seg, s-half)
__global__ __launch_bounds__(256) void k_Cm(const unsigned short* __restrict__ LinkTb,
                                            const unsigned short* __restrict__ Bt,
                                            float* __restrict__ out) {
  __shared__ float red[4][16][32];      // 8 KB
  const int bid = blockIdx.x;
  const int ct = bid & 7;
  const int tt = (bid >> 3) & 31;
  const int b  = bid >> 8;
  const int t0 = tt * 16;
  const int d0 = ct * 32;
  const int w  = threadIdx.x >> 6;
  const int l  = threadIdx.x & 63;
  const int m  = l & 15, q = l >> 4;
  const int seg = w >> 1;               // 0: Linker*T, 1: rLinker*rfeat
  const int sh  = w & 1;                // s-half within seg

  f32x4 acc0 = {}, acc1 = {};
  const unsigned short* Arow = LinkTb + (size_t)(t0 + m) * 2048 + seg * 1024 + sh * 512 + q * 8;
  const unsigned short* Brow = Bt + (size_t)(d0 + m) * 4096 + seg * 2048 + b * 1024 + sh * 512 + q * 8;

  #pragma unroll
  for (int ks = 0; ks < 16; ++ks) {
    const bf16x8 a0 = *(const bf16x8*)(Arow + ks * 32);
    const bf16x8 b0 = *(const bf16x8*)(Brow + ks * 32);
    const bf16x8 b1 = *(const bf16x8*)(Brow + 16 * 4096 + ks * 32);
    acc0 = __builtin_amdgcn_mfma_f32_16x16x32_bf16(a0, b0, acc0, 0, 0, 0);
    acc1 = __builtin_amdgcn_mfma_f32_16x16x32_bf16(a0, b1, acc1, 0, 0, 0);
  }

  #pragma unroll
  for (int r = 0; r < 4; ++r) {
    red[w][q * 4 + r][m]      = acc0[r];
    red[w][q * 4 + r][16 + m] = acc1[r];
  }
  __syncthreads();

  const int row = threadIdx.x >> 4;
  const int c0  = (threadIdx.x & 15) * 2;
  float2 s;
  s.x = red[0][row][c0] + red[1][row][c0] + red[2][row][c0] + red[3][row][c0];
  s.y = red[0][row][c0 + 1] + red[1][row][c0 + 1] + red[2][row][c0 + 1] + red[3][row][c0 + 1];
  *(float2*)&out[(size_t)(b * 512 + t0 + row) * D256 + d0 + c0] = s;
}

extern "C" void kernel_launch(void* const* d_in, const int* in_sizes, int n_in,
                              void* d_out, int out_size, void* d_ws, size_t ws_size,
                              hipStream_t stream) {
  const float* x       = (const float*)d_in[0];
  const float* M       = (const float*)d_in[1];
  const float* P       = (const float*)d_in[2];
  const float* Linker  = (const float*)d_in[3];
  const float* gamma   = (const float*)d_in[4];
  const float* beta    = (const float*)d_in[5];
  const float* resW    = (const float*)d_in[6];
  const float* rLinker = (const float*)d_in[7];
  float* out = (float*)d_out;

  char* ws = (char*)d_ws;
  float4*         PIt4   = (float4*)(ws);                           // 1 MB
  unsigned short* LinkTb = (unsigned short*)(ws + 1024 * 1024);     // 2 MB
  unsigned short* Bt     = (unsigned short*)(ws + 3072 * 1024);     // 2 MB
  unsigned short* xb     = (unsigned short*)(ws + 5120 * 1024);     // 1 MB
  unsigned short* Mb     = (unsigned short*)(ws + 6144 * 1024);     // 128 KB
  unsigned short* Wb     = (unsigned short*)(ws + 6272 * 1024);     // 128 KB
  float*          Zb     = (float*)(ws + 6400 * 1024);              // 2 MB

  hipLaunchKernelGGL(k_prep, dim3(832),  dim3(256), 0, stream,
                     x, M, resW, P, Linker, rLinker, PIt4, LinkTb, xb, Mb, Wb);
  hipLaunchKernelGGL(k_Azn,  dim3(128),  dim3(256), 0, stream,
                     xb, Mb, Wb, gamma, beta, Zb, Bt);
  hipLaunchKernelGGL(k_B,    dim3(4096), dim3(256), 0, stream, Zb, PIt4, Bt);
  hipLaunchKernelGGL(k_Cm,   dim3(512),  dim3(256), 0, stream, LinkTb, Bt, out);
}

// Round 13
// 56.112 us; speedup vs baseline: 1.3083x; 1.3083x over previous
//
#include <hip/hip_runtime.h>

#define D256 256
#define S_SEQ 1024
#define OUTSEQ 512

typedef __attribute__((ext_vector_type(8))) short bf16x8;
typedef __attribute__((ext_vector_type(8))) unsigned short u16x8;
typedef __attribute__((ext_vector_type(4))) float f32x4;
typedef __attribute__((ext_vector_type(2))) float f32x2;

__device__ inline unsigned short f2bf(float f) {          // RNE fp32->bf16
  unsigned u = __float_as_uint(f);
  return (unsigned short)((u + 0x7fffu + ((u >> 16) & 1u)) >> 16);
}

// ---------------- prep ----------------
// blocks   0..255 : PIt4[j][i] = {P[i][j], 1/p, cb2, D}, p = i*256+j+2
//                   cb2 = 2cos(2pi/p), D = cb2^2-2 = 2cos(4pi/p)
// blocks 256..511 : LinkTb[t][s] = bf16( s<1024 ? Linker[s][t] : rLinker[s-1024][t] )
// blocks 512..767 : xb  = bf16(x)   blocks 768..799: Mb   blocks 800..831: Wb
__global__ __launch_bounds__(256) void k_prep(const float* __restrict__ x,
                                              const float* __restrict__ M,
                                              const float* __restrict__ resW,
                                              const float* __restrict__ P,
                                              const float* __restrict__ Linker,
                                              const float* __restrict__ rLinker,
                                              float4* __restrict__ PIt4,
                                              unsigned short* __restrict__ LinkTb,
                                              unsigned short* __restrict__ xb,
                                              unsigned short* __restrict__ Mb,
                                              unsigned short* __restrict__ Wb) {
  __shared__ float tl[64][65];
  const int tid = threadIdx.x;
  const int blk = blockIdx.x;
  if (blk < 256) {
    const int j = blk;
    const int t = tid;
    const float p = (float)(t * D256 + j + 2);
    const float ip = 1.0f / p;
    const float cb2 = 2.0f * __builtin_amdgcn_cosf(ip);   // v_cos takes revolutions
    const float D = fmaf(cb2, cb2, -2.0f);                // 2cos(4pi/p)
    PIt4[j * D256 + t] = make_float4(P[t * D256 + j], ip, cb2, D);
    return;
  }
  if (blk >= 512) {                     // flat fp32 -> bf16 converts
    const float* src;
    unsigned short* dst;
    size_t base;
    if (blk < 768)      { src = x;    dst = xb; base = (size_t)(blk - 512) * 2048; }
    else if (blk < 800) { src = M;    dst = Mb; base = (size_t)(blk - 768) * 2048; }
    else                { src = resW; dst = Wb; base = (size_t)(blk - 800) * 2048; }
    const size_t off = base + (size_t)tid * 8;
    const float4 v0 = *(const float4*)(src + off);
    const float4 v1 = *(const float4*)(src + off + 4);
    u16x8 o;
    o[0] = f2bf(v0.x); o[1] = f2bf(v0.y); o[2] = f2bf(v0.z); o[3] = f2bf(v0.w);
    o[4] = f2bf(v1.x); o[5] = f2bf(v1.y); o[6] = f2bf(v1.z); o[7] = f2bf(v1.w);
    *(u16x8*)(dst + off) = o;
    return;
  }
  // LinkTb transpose-pack
  const int tb = blk - 256;
  const int st = tb & 31;
  const int tt = tb >> 5;
  const int s0 = st * 64, t0 = tt * 64;
  const float* src = (s0 < 1024) ? (Linker + (size_t)s0 * OUTSEQ)
                                 : (rLinker + (size_t)(s0 - 1024) * OUTSEQ);
  {
    const int sy = tid >> 2, sx = tid & 3;
    #pragma unroll
    for (int c = 0; c < 4; ++c) {
      const int ci = sx + c * 4;
      const float4 v = *(const float4*)&src[sy * OUTSEQ + t0 + ci * 4];
      tl[ci * 4 + 0][sy] = v.x;
      tl[ci * 4 + 1][sy] = v.y;
      tl[ci * 4 + 2][sy] = v.z;
      tl[ci * 4 + 3][sy] = v.w;
    }
  }
  __syncthreads();
  {
    const int ty = tid >> 2, tx = tid & 3;
    u16x8 o0, o1;
    #pragma unroll
    for (int e = 0; e < 8; ++e) o0[e] = f2bf(tl[ty][tx * 16 + e]);
    #pragma unroll
    for (int e = 0; e < 8; ++e) o1[e] = f2bf(tl[ty][tx * 16 + 8 + e]);
    unsigned short* dst = LinkTb + (size_t)(t0 + ty) * 2048 + s0 + tx * 16;
    *(u16x8*)dst = o0;
    *(u16x8*)(dst + 8) = o1;
  }
}

// ---------------- k_Azn: MFMA phase A + LN -> ZbT [j][k] ----------------
__global__ __launch_bounds__(256) void k_Azn(const unsigned short* __restrict__ xb,
                                             const unsigned short* __restrict__ Mb,
                                             const unsigned short* __restrict__ Wb,
                                             const float* __restrict__ gamma,
                                             const float* __restrict__ beta,
                                             float* __restrict__ ZbT,
                                             unsigned short* __restrict__ Bt) {
  __shared__ float Zs[16][D256];
  __shared__ float Rs[16][D256];
  __shared__ float mu_s[16], rs_s[16];
  const int k0 = blockIdx.x * 16;
  const int w = threadIdx.x >> 6;
  const int l = threadIdx.x & 63;
  const int m = l & 15, q = l >> 4;

  f32x4 aZ[4] = {}, aR[4] = {};
  const unsigned short* Arow = xb + (size_t)(k0 + m) * D256;
  #pragma unroll
  for (int ks = 0; ks < 8; ++ks) {
    const bf16x8 a = *(const bf16x8*)(Arow + ks * 32 + q * 8);
    #pragma unroll
    for (int cf = 0; cf < 4; ++cf) {
      const int o = w * 64 + cf * 16 + m;
      const bf16x8 bz = *(const bf16x8*)(Mb + (size_t)o * D256 + ks * 32 + q * 8);
      const bf16x8 br = *(const bf16x8*)(Wb + (size_t)o * D256 + ks * 32 + q * 8);
      aZ[cf] = __builtin_amdgcn_mfma_f32_16x16x32_bf16(a, bz, aZ[cf], 0, 0, 0);
      aR[cf] = __builtin_amdgcn_mfma_f32_16x16x32_bf16(a, br, aR[cf], 0, 0, 0);
    }
  }
  #pragma unroll
  for (int cf = 0; cf < 4; ++cf) {
    #pragma unroll
    for (int r = 0; r < 4; ++r) {
      Zs[q * 4 + r][w * 64 + cf * 16 + m] = aZ[cf][r];
      Rs[q * 4 + r][w * 64 + cf * 16 + m] = aR[cf][r];
    }
  }
  __syncthreads();

  #pragma unroll
  for (int rr = w; rr < 16; rr += 4) {
    float s = 0.f, sq = 0.f;
    #pragma unroll
    for (int p = 0; p < 4; ++p) {
      const float v = Zs[rr][l + 64 * p];
      s += v;
      sq = fmaf(v, v, sq);
    }
    #pragma unroll
    for (int off = 32; off; off >>= 1) {
      s += __shfl_down(s, off);
      sq += __shfl_down(sq, off);
    }
    if (l == 0) {
      const float mu = s * (1.0f / 256.0f);
      const float var = sq * (1.0f / 256.0f) - mu * mu;
      mu_s[rr] = mu;
      rs_s[rr] = rsqrtf(var + 1e-5f);
    }
  }
  __syncthreads();

  {
    const int t = threadIdx.x;
    const float g = gamma[t], be = beta[t];
    float zt[16];
    u16x8 o0, o1;
    #pragma unroll
    for (int rr = 0; rr < 16; ++rr) {
      zt[rr] = (Zs[rr][t] - mu_s[rr]) * rs_s[rr] * g + be;
      const unsigned short rb = f2bf(Rs[rr][t]);
      if (rr < 8) o0[rr] = rb; else o1[rr - 8] = rb;
    }
    float* zd = ZbT + (size_t)t * 2048 + k0;      // transposed: [j=t][k]
    *(float4*)(zd + 0)  = make_float4(zt[0], zt[1], zt[2], zt[3]);
    *(float4*)(zd + 4)  = make_float4(zt[4], zt[5], zt[6], zt[7]);
    *(float4*)(zd + 8)  = make_float4(zt[8], zt[9], zt[10], zt[11]);
    *(float4*)(zd + 12) = make_float4(zt[12], zt[13], zt[14], zt[15]);
    unsigned short* dst = Bt + (size_t)t * 4096 + 2048 + k0;
    *(u16x8*)dst = o0;
    *(u16x8*)(dst + 8) = o1;
  }
}

// ---------------- k_B: packed double-step Chebyshev cos-einsum ----------------
// grid 2048 = (k-tile kt of 32) x (i-group ig of 8); 256 thr = jg(32) x il(8)
// thread: i = ig*8+il, j in {jg*8 .. jg*8+7}; 16 f32x2 accs (32 k).
// Pair recurrence: P_{m+1} = D*P_m - P_{m-1}, D = 2cos(4pi/p) from table.
__global__ __launch_bounds__(256, 4) void k_B(const float* __restrict__ ZbT,
                                              const float4* __restrict__ PIt4,
                                              unsigned short* __restrict__ Bt) {
  __shared__ float buf[8448];           // 33 KB reduce buffer [jg*264 + il*33 + k]
  const int tid = threadIdx.x;
  const int il = tid & 7;
  const int jg = tid >> 3;              // 0..31
  const int ig = blockIdx.x & 31;
  const int kt = blockIdx.x >> 5;       // 0..63
  const int i0 = ig * 8;
  const int k0 = kt * 32;
  const int i  = i0 + il;

  f32x2 acc[16];
  #pragma unroll
  for (int q = 0; q < 16; ++q) acc[q] = (f32x2){0.f, 0.f};

  const float kf0 = (float)k0;
  #pragma unroll
  for (int jj = 0; jj < 8; ++jj) {
    const int j = jg * 8 + jj;
    const f32x4 pi = *(const f32x4*)&PIt4[(size_t)j * D256 + i];   // {P, ip, cb2, D}
    const float* zr = ZbT + (size_t)j * 2048 + k0;                 // one 128B line
    const f32x4 z0 = *(const f32x4*)(zr + 0);
    const f32x4 z1 = *(const f32x4*)(zr + 4);
    const f32x4 z2 = *(const f32x4*)(zr + 8);
    const f32x4 z3 = *(const f32x4*)(zr + 12);
    const f32x4 z4 = *(const f32x4*)(zr + 16);
    const f32x4 z5 = *(const f32x4*)(zr + 20);
    const f32x4 z6 = *(const f32x4*)(zr + 24);
    const f32x4 z7 = *(const f32x4*)(zr + 28);
    const float a  = kf0 * pi.y;
    const float r0 = __builtin_amdgcn_fractf(a);
    const float r1 = __builtin_amdgcn_fractf(a + pi.y);
    const float s0 = __builtin_amdgcn_cosf(r0) * pi.x;   // P folded into seeds
    const float s1 = __builtin_amdgcn_cosf(r1) * pi.x;
    const float s2 = fmaf(pi.z, s1, -s0);
    const float s3 = fmaf(pi.z, s2, -s1);
    f32x2 pm1 = {s0, s1};
    f32x2 pm  = {s2, s3};
    const f32x2 D2 = {pi.w, pi.w};
    acc[0] = __builtin_elementwise_fma((f32x2){z0.x, z0.y}, pm1, acc[0]);
    acc[1] = __builtin_elementwise_fma((f32x2){z0.z, z0.w}, pm,  acc[1]);
    f32x2 pn;
#define CSTEP(IDX, ZA, ZB) \
    pn = __builtin_elementwise_fma(D2, pm, -pm1); \
    acc[IDX] = __builtin_elementwise_fma((f32x2){ZA, ZB}, pn, acc[IDX]); \
    pm1 = pm; pm = pn;
    CSTEP(2,  z1.x, z1.y)
    CSTEP(3,  z1.z, z1.w)
    CSTEP(4,  z2.x, z2.y)
    CSTEP(5,  z2.z, z2.w)
    CSTEP(6,  z3.x, z3.y)
    CSTEP(7,  z3.z, z3.w)
    CSTEP(8,  z4.x, z4.y)
    CSTEP(9,  z4.z, z4.w)
    CSTEP(10, z5.x, z5.y)
    CSTEP(11, z5.z, z5.w)
    CSTEP(12, z6.x, z6.y)
    CSTEP(13, z6.z, z6.w)
    CSTEP(14, z7.x, z7.y)
    CSTEP(15, z7.z, z7.w)
#undef CSTEP
  }

  // jg-reduce: layout banks = (8jg + il + 2k) % 32 -> <=2-way, free
  #pragma unroll
  for (int k2 = 0; k2 < 16; ++k2) {
    buf[jg * 264 + il * 33 + k2 * 2]     = acc[k2].x;
    buf[jg * 264 + il * 33 + k2 * 2 + 1] = acc[k2].y;
  }
  __syncthreads();

  // tid -> (ir = tid>>5, kr = tid&31); reads 2-way max; direct bf16 store
  const int ir = tid >> 5, kr = tid & 31;
  float tv = 0.f;
  #pragma unroll
  for (int g = 0; g < 32; ++g) tv += buf[g * 264 + ir * 33 + kr];
  Bt[(size_t)(i0 + ir) * 4096 + k0 + kr] = f2bf(tv);
}

// ---------------- k_Cm: bf16 MFMA GEMM, K split 8 ways ----------------
__global__ __launch_bounds__(256) void k_Cm(const unsigned short* __restrict__ LinkTb,
                                            const unsigned short* __restrict__ Bt,
                                            float* __restrict__ part) {
  const int bid = blockIdx.x;
  const int kc = bid & 7;
  const int dt = (bid >> 3) & 3;
  const int tt = (bid >> 5) & 7;
  const int b  = bid >> 8;
  const int wv = threadIdx.x >> 6;
  const int l  = threadIdx.x & 63;
  const int wm = wv >> 1, wn = wv & 1;
  const int t0 = tt * 64 + wm * 32;
  const int d0 = dt * 64 + wn * 32;
  const int m  = l & 15;
  const int q  = l >> 4;
  const int sc0 = kc * 128;

  f32x4 acc00 = {}, acc01 = {}, acc10 = {}, acc11 = {};
  const unsigned short* Arow = LinkTb + (size_t)(t0 + m) * 2048;
  const unsigned short* Brow = Bt + (size_t)(d0 + m) * 4096;

  #pragma unroll
  for (int seg = 0; seg < 2; ++seg) {
    const int acol = seg * 1024 + sc0 + q * 8;
    const int bcol = seg * 2048 + b * 1024 + sc0 + q * 8;
    #pragma unroll
    for (int ks = 0; ks < 4; ++ks) {
      const bf16x8 a0 = *(const bf16x8*)(Arow + acol + ks * 32);
      const bf16x8 a1 = *(const bf16x8*)(Arow + 16 * 2048 + acol + ks * 32);
      const bf16x8 b0 = *(const bf16x8*)(Brow + bcol + ks * 32);
      const bf16x8 b1 = *(const bf16x8*)(Brow + 16 * 4096 + bcol + ks * 32);
      acc00 = __builtin_amdgcn_mfma_f32_16x16x32_bf16(a0, b0, acc00, 0, 0, 0);
      acc01 = __builtin_amdgcn_mfma_f32_16x16x32_bf16(a0, b1, acc01, 0, 0, 0);
      acc10 = __builtin_amdgcn_mfma_f32_16x16x32_bf16(a1, b0, acc10, 0, 0, 0);
      acc11 = __builtin_amdgcn_mfma_f32_16x16x32_bf16(a1, b1, acc11, 0, 0, 0);
    }
  }

  float* pb = part + ((size_t)kc << 18) + (size_t)(b * 512 + t0 + q * 4) * D256 + d0 + m;
  #pragma unroll
  for (int reg = 0; reg < 4; ++reg) {
    pb[(0 + reg) * D256 + 0]   = acc00[reg];
    pb[(0 + reg) * D256 + 16]  = acc01[reg];
    pb[(16 + reg) * D256 + 0]  = acc10[reg];
    pb[(16 + reg) * D256 + 16] = acc11[reg];
  }
}

// ---------------- k_Cred: sum the 8 K-chunk partials ----------------
__global__ __launch_bounds__(256) void k_Cred(const float* __restrict__ part,
                                              float* __restrict__ out) {
  const int row = blockIdx.x;
  const int d   = threadIdx.x;
  float s = 0.f;
  #pragma unroll
  for (int kc = 0; kc < 8; ++kc)
    s += part[((size_t)kc << 18) + row * D256 + d];
  out[row * D256 + d] = s;
}

extern "C" void kernel_launch(void* const* d_in, const int* in_sizes, int n_in,
                              void* d_out, int out_size, void* d_ws, size_t ws_size,
                              hipStream_t stream) {
  const float* x       = (const float*)d_in[0];
  const float* M       = (const float*)d_in[1];
  const float* P       = (const float*)d_in[2];
  const float* Linker  = (const float*)d_in[3];
  const float* gamma   = (const float*)d_in[4];
  const float* beta    = (const float*)d_in[5];
  const float* resW    = (const float*)d_in[6];
  const float* rLinker = (const float*)d_in[7];
  float* out = (float*)d_out;

  char* ws = (char*)d_ws;
  float4*         PIt4   = (float4*)(ws);                           // 1 MB
  unsigned short* LinkTb = (unsigned short*)(ws + 1024 * 1024);     // 2 MB
  unsigned short* Bt     = (unsigned short*)(ws + 3072 * 1024);     // 2 MB
  unsigned short* xb     = (unsigned short*)(ws + 5120 * 1024);     // 1 MB
  unsigned short* Mb     = (unsigned short*)(ws + 6144 * 1024);     // 128 KB
  unsigned short* Wb     = (unsigned short*)(ws + 6272 * 1024);     // 128 KB
  float*          ZbT    = (float*)(ws + 6400 * 1024);              // 2 MB
  float*          part   = (float*)(ws + 8448 * 1024);              // 8 MB

  hipLaunchKernelGGL(k_prep, dim3(832),  dim3(256), 0, stream,
                     x, M, resW, P, Linker, rLinker, PIt4, LinkTb, xb, Mb, Wb);
  hipLaunchKernelGGL(k_Azn,  dim3(128),  dim3(256), 0, stream,
                     xb, Mb, Wb, gamma, beta, ZbT, Bt);
  hipLaunchKernelGGL(k_B,    dim3(2048), dim3(256), 0, stream, ZbT, PIt4, Bt);
  hipLaunchKernelGGL(k_Cm,   dim3(512),  dim3(256), 0, stream, LinkTb, Bt, part);
  hipLaunchKernelGGL(k_Cred, dim3(1024), dim3(256), 0, stream, part, out);
}

// Round 14
// 49.463 us; speedup vs baseline: 1.4841x; 1.1344x over previous
//
#include <hip/hip_runtime.h>

#define D256 256
#define S_SEQ 1024
#define OUTSEQ 512

typedef __attribute__((ext_vector_type(8))) short bf16x8;
typedef __attribute__((ext_vector_type(8))) unsigned short u16x8;
typedef __attribute__((ext_vector_type(4))) unsigned short u16x4;
typedef __attribute__((ext_vector_type(4))) float f32x4;
typedef __attribute__((ext_vector_type(2))) float f32x2;

__device__ inline unsigned short f2bf(float f) {          // RNE fp32->bf16
  unsigned u = __float_as_uint(f);
  return (unsigned short)((u + 0x7fffu + ((u >> 16) & 1u)) >> 16);
}

// ---------------- prep ----------------
// blocks   0..255 : PIt4[j][i] = {P[i][j], 1/p, cb2, D}, p = i*256+j+2
//                   cb2 = 2cos(2pi/p), D = cb2^2-2 = 2cos(4pi/p)
// blocks 256..511 : LinkTb[t][s] = bf16( s<1024 ? Linker[s][t] : rLinker[s-1024][t] )
// blocks 512..767 : xb = bf16(x)   768..799: Mb   800..831: Wb
__global__ __launch_bounds__(256) void k_prep(const float* __restrict__ x,
                                              const float* __restrict__ M,
                                              const float* __restrict__ resW,
                                              const float* __restrict__ P,
                                              const float* __restrict__ Linker,
                                              const float* __restrict__ rLinker,
                                              float4* __restrict__ PIt4,
                                              unsigned short* __restrict__ LinkTb,
                                              unsigned short* __restrict__ xb,
                                              unsigned short* __restrict__ Mb,
                                              unsigned short* __restrict__ Wb) {
  __shared__ float tl[64][65];
  const int tid = threadIdx.x;
  const int blk = blockIdx.x;
  if (blk < 256) {
    const int j = blk;
    const int t = tid;
    const float p = (float)(t * D256 + j + 2);
    const float ip = 1.0f / p;
    const float cb2 = 2.0f * __builtin_amdgcn_cosf(ip);   // v_cos takes revolutions
    const float D = fmaf(cb2, cb2, -2.0f);                // 2cos(4pi/p)
    PIt4[j * D256 + t] = make_float4(P[t * D256 + j], ip, cb2, D);
    return;
  }
  if (blk >= 512) {                     // flat fp32 -> bf16 converts
    const float* src;
    unsigned short* dst;
    size_t base;
    if (blk < 768)      { src = x;    dst = xb; base = (size_t)(blk - 512) * 2048; }
    else if (blk < 800) { src = M;    dst = Mb; base = (size_t)(blk - 768) * 2048; }
    else                { src = resW; dst = Wb; base = (size_t)(blk - 800) * 2048; }
    const size_t off = base + (size_t)tid * 8;
    const float4 v0 = *(const float4*)(src + off);
    const float4 v1 = *(const float4*)(src + off + 4);
    u16x8 o;
    o[0] = f2bf(v0.x); o[1] = f2bf(v0.y); o[2] = f2bf(v0.z); o[3] = f2bf(v0.w);
    o[4] = f2bf(v1.x); o[5] = f2bf(v1.y); o[6] = f2bf(v1.z); o[7] = f2bf(v1.w);
    *(u16x8*)(dst + off) = o;
    return;
  }
  // LinkTb transpose-pack
  const int tb = blk - 256;             // 0..255
  const int st = tb & 31;               // s-tile (64 rows)
  const int tt = tb >> 5;               // t-tile (64 cols)
  const int s0 = st * 64, t0 = tt * 64;
  const float* src = (s0 < 1024) ? (Linker + (size_t)s0 * OUTSEQ)
                                 : (rLinker + (size_t)(s0 - 1024) * OUTSEQ);
  {
    const int sy = tid >> 2, sx = tid & 3;
    #pragma unroll
    for (int c = 0; c < 4; ++c) {
      const int ci = sx + c * 4;
      const float4 v = *(const float4*)&src[sy * OUTSEQ + t0 + ci * 4];
      tl[ci * 4 + 0][sy] = v.x;
      tl[ci * 4 + 1][sy] = v.y;
      tl[ci * 4 + 2][sy] = v.z;
      tl[ci * 4 + 3][sy] = v.w;
    }
  }
  __syncthreads();
  {
    const int ty = tid >> 2, tx = tid & 3;
    u16x8 o0, o1;
    #pragma unroll
    for (int e = 0; e < 8; ++e) o0[e] = f2bf(tl[ty][tx * 16 + e]);
    #pragma unroll
    for (int e = 0; e < 8; ++e) o1[e] = f2bf(tl[ty][tx * 16 + 8 + e]);
    unsigned short* dst = LinkTb + (size_t)(t0 + ty) * 2048 + s0 + tx * 16;
    *(u16x8*)dst = o0;
    *(u16x8*)(dst + 8) = o1;
  }
}

// ---------------- k_Azn: MFMA phase A + LN ----------------
// grid 128 (k-tiles of 16), 256 thr = 4 waves; wave w owns o-cols [w*64, w*64+64)
// Zpre = x@M^T -> LN -> Zb fp32 [k][i];  rfeat = x@resW^T -> Bt[d][2048+k] bf16
__global__ __launch_bounds__(256) void k_Azn(const unsigned short* __restrict__ xb,
                                             const unsigned short* __restrict__ Mb,
                                             const unsigned short* __restrict__ Wb,
                                             const float* __restrict__ gamma,
                                             const float* __restrict__ beta,
                                             float* __restrict__ Zb,
                                             unsigned short* __restrict__ Bt) {
  __shared__ float Zs[16][D256];
  __shared__ float Rs[16][D256];
  __shared__ float mu_s[16], rs_s[16];
  const int k0 = blockIdx.x * 16;
  const int w = threadIdx.x >> 6;
  const int l = threadIdx.x & 63;
  const int m = l & 15, q = l >> 4;

  f32x4 aZ[4] = {}, aR[4] = {};
  const unsigned short* Arow = xb + (size_t)(k0 + m) * D256;
  #pragma unroll
  for (int ks = 0; ks < 8; ++ks) {
    const bf16x8 a = *(const bf16x8*)(Arow + ks * 32 + q * 8);
    #pragma unroll
    for (int cf = 0; cf < 4; ++cf) {
      const int o = w * 64 + cf * 16 + m;
      const bf16x8 bz = *(const bf16x8*)(Mb + (size_t)o * D256 + ks * 32 + q * 8);
      const bf16x8 br = *(const bf16x8*)(Wb + (size_t)o * D256 + ks * 32 + q * 8);
      aZ[cf] = __builtin_amdgcn_mfma_f32_16x16x32_bf16(a, bz, aZ[cf], 0, 0, 0);
      aR[cf] = __builtin_amdgcn_mfma_f32_16x16x32_bf16(a, br, aR[cf], 0, 0, 0);
    }
  }
  #pragma unroll
  for (int cf = 0; cf < 4; ++cf) {
    #pragma unroll
    for (int r = 0; r < 4; ++r) {
      Zs[q * 4 + r][w * 64 + cf * 16 + m] = aZ[cf][r];
      Rs[q * 4 + r][w * 64 + cf * 16 + m] = aR[cf][r];
    }
  }
  __syncthreads();

  // LN stats: wave w reduces rows {w, w+4, w+8, w+12}
  #pragma unroll
  for (int rr = w; rr < 16; rr += 4) {
    float s = 0.f, sq = 0.f;
    #pragma unroll
    for (int p = 0; p < 4; ++p) {
      const float v = Zs[rr][l + 64 * p];
      s += v;
      sq = fmaf(v, v, sq);
    }
    #pragma unroll
    for (int off = 32; off; off >>= 1) {
      s += __shfl_down(s, off);
      sq += __shfl_down(sq, off);
    }
    if (l == 0) {
      const float mu = s * (1.0f / 256.0f);
      const float var = sq * (1.0f / 256.0f) - mu * mu;
      mu_s[rr] = mu;
      rs_s[rr] = rsqrtf(var + 1e-5f);
    }
  }
  __syncthreads();

  // normalize -> Zb fp32; pack rfeat -> Bt bf16 transposed
  {
    const int t = threadIdx.x;
    const float g = gamma[t], be = beta[t];
    u16x8 o0, o1;
    #pragma unroll
    for (int rr = 0; rr < 16; ++rr) {
      Zb[(size_t)(k0 + rr) * D256 + t] = (Zs[rr][t] - mu_s[rr]) * rs_s[rr] * g + be;
      const unsigned short rb = f2bf(Rs[rr][t]);
      if (rr < 8) o0[rr] = rb; else o1[rr - 8] = rb;
    }
    unsigned short* dst = Bt + (size_t)t * 4096 + 2048 + k0;
    *(u16x8*)dst = o0;
    *(u16x8*)(dst + 8) = o1;
  }
}

// ---------------- k_B: cos-einsum, paired Chebyshev (pk-fma) ----------------
// R10 skeleton: grid 4096 = kt(128) x ig(32); 256 thr = jg(32) x il(8);
// thread: i = ig*8+il, j in {jg + 32*jj}; 16 k per tile as 8 f32x2 pairs.
// Pair recurrence: P_{m+1} = D*P_m - P_{m-1}, D = 2cos(4pi/p) (PIt4.w).
__global__ __launch_bounds__(256, 6) void k_B(const float* __restrict__ Zb,
                                              const float4* __restrict__ PIt4,
                                              unsigned short* __restrict__ Bt) {
  __shared__ float buf[5120];           // 20 KB
  const int tid = threadIdx.x;
  const int il = tid & 7;
  const int jg = tid >> 3;              // 0..31
  const int ig = blockIdx.x & 31;
  const int kt = blockIdx.x >> 5;
  const int i0 = ig * 8;
  const int k0 = kt * 16;
  const int i  = i0 + il;

  // stage Z tile: buf[j*20 + k] = Zb[k0+k][j]   (coalesced global reads)
  #pragma unroll
  for (int r = 0; r < 16; ++r)
    buf[tid * 20 + r] = Zb[(size_t)(k0 + r) * D256 + tid];
  __syncthreads();

  f32x2 acc[8];
  #pragma unroll
  for (int q = 0; q < 8; ++q) acc[q] = (f32x2){0.f, 0.f};

  const float kf0 = (float)k0;
  const f32x4* pip = (const f32x4*)(PIt4 + i);
  #pragma unroll
  for (int jj = 0; jj < 8; ++jj) {
    const int j = jg + 32 * jj;                    // stride-32 j: bank-clean b128 reads
    const f32x4 pi = pip[(size_t)j * D256];        // {P, 1/p, cb2, D}
    const float4 z0 = *(const float4*)&buf[j * 20 + 0];   // 8-lane broadcast groups
    const float4 z1 = *(const float4*)&buf[j * 20 + 4];
    const float4 z2 = *(const float4*)&buf[j * 20 + 8];
    const float4 z3 = *(const float4*)&buf[j * 20 + 12];
    const float a  = kf0 * pi.y;
    const float r0 = __builtin_amdgcn_fractf(a);
    const float r1 = __builtin_amdgcn_fractf(a + pi.y);
    const float s0 = __builtin_amdgcn_cosf(r0) * pi.x;    // P folded into seeds
    const float s1 = __builtin_amdgcn_cosf(r1) * pi.x;
    const float s2 = fmaf(pi.z, s1, -s0);
    const float s3 = fmaf(pi.z, s2, -s1);
    f32x2 P0 = {s0, s1};
    f32x2 P1 = {s2, s3};
    const f32x2 D2 = {pi.w, pi.w};
    acc[0] = __builtin_elementwise_fma((f32x2){z0.x, z0.y}, P0, acc[0]);
    acc[1] = __builtin_elementwise_fma((f32x2){z0.z, z0.w}, P1, acc[1]);
    f32x2 Pn;
#define CSTEP(IDX, ZA, ZB) \
    Pn = __builtin_elementwise_fma(D2, P1, -P0); \
    acc[IDX] = __builtin_elementwise_fma((f32x2){ZA, ZB}, Pn, acc[IDX]); \
    P0 = P1; P1 = Pn;
    CSTEP(2, z1.x, z1.y)
    CSTEP(3, z1.z, z1.w)
    CSTEP(4, z2.x, z2.y)
    CSTEP(5, z2.z, z2.w)
    CSTEP(6, z3.x, z3.y)
    CSTEP(7, z3.z, z3.w)
#undef CSTEP
  }
  __syncthreads();                      // Z reads done; reuse buf as red

  #pragma unroll
  for (int k2 = 0; k2 < 8; ++k2) {
    buf[jg * 132 + (k2 * 2) * 8 + il]     = acc[k2].x;   // same layout as R10
    buf[jg * 132 + (k2 * 2 + 1) * 8 + il] = acc[k2].y;
  }
  __syncthreads();

  float tv = 0.f;
  if (tid < 128) {                      // tid = k*8 + il
    #pragma unroll
    for (int g = 0; g < 32; ++g) tv += buf[g * 132 + tid];
  }
  __syncthreads();
  if (tid < 128) buf[(tid & 7) * 16 + (tid >> 3)] = tv;   // outT[il][k]
  __syncthreads();
  if (tid < 32) {
    const int iw = tid >> 2;
    const int kq = tid & 3;
    const float4 v = *(const float4*)&buf[iw * 16 + kq * 4];
    u16x4 o;
    o[0] = f2bf(v.x); o[1] = f2bf(v.y); o[2] = f2bf(v.z); o[3] = f2bf(v.w);
    *(u16x4*)(Bt + (size_t)(i0 + iw) * 4096 + k0 + kq * 4) = o;
  }
}

// ---------------- k_Cm: bf16 MFMA GEMM, K split 8 ways ----------------
__global__ __launch_bounds__(256) void k_Cm(const unsigned short* __restrict__ LinkTb,
                                            const unsigned short* __restrict__ Bt,
                                            float* __restrict__ part) {
  const int bid = blockIdx.x;
  const int kc = bid & 7;
  const int dt = (bid >> 3) & 3;
  const int tt = (bid >> 5) & 7;
  const int b  = bid >> 8;
  const int wv = threadIdx.x >> 6;
  const int l  = threadIdx.x & 63;
  const int wm = wv >> 1, wn = wv & 1;
  const int t0 = tt * 64 + wm * 32;
  const int d0 = dt * 64 + wn * 32;
  const int m  = l & 15;
  const int q  = l >> 4;
  const int sc0 = kc * 128;

  f32x4 acc00 = {}, acc01 = {}, acc10 = {}, acc11 = {};
  const unsigned short* Arow = LinkTb + (size_t)(t0 + m) * 2048;
  const unsigned short* Brow = Bt + (size_t)(d0 + m) * 4096;

  #pragma unroll
  for (int seg = 0; seg < 2; ++seg) {
    const int acol = seg * 1024 + sc0 + q * 8;
    const int bcol = seg * 2048 + b * 1024 + sc0 + q * 8;
    #pragma unroll
    for (int ks = 0; ks < 4; ++ks) {
      const bf16x8 a0 = *(const bf16x8*)(Arow + acol + ks * 32);
      const bf16x8 a1 = *(const bf16x8*)(Arow + 16 * 2048 + acol + ks * 32);
      const bf16x8 b0 = *(const bf16x8*)(Brow + bcol + ks * 32);
      const bf16x8 b1 = *(const bf16x8*)(Brow + 16 * 4096 + bcol + ks * 32);
      acc00 = __builtin_amdgcn_mfma_f32_16x16x32_bf16(a0, b0, acc00, 0, 0, 0);
      acc01 = __builtin_amdgcn_mfma_f32_16x16x32_bf16(a0, b1, acc01, 0, 0, 0);
      acc10 = __builtin_amdgcn_mfma_f32_16x16x32_bf16(a1, b0, acc10, 0, 0, 0);
      acc11 = __builtin_amdgcn_mfma_f32_16x16x32_bf16(a1, b1, acc11, 0, 0, 0);
    }
  }

  float* pb = part + ((size_t)kc << 18) + (size_t)(b * 512 + t0 + q * 4) * D256 + d0 + m;
  #pragma unroll
  for (int reg = 0; reg < 4; ++reg) {
    pb[(0 + reg) * D256 + 0]   = acc00[reg];
    pb[(0 + reg) * D256 + 16]  = acc01[reg];
    pb[(16 + reg) * D256 + 0]  = acc10[reg];
    pb[(16 + reg) * D256 + 16] = acc11[reg];
  }
}

// ---------------- k_Cred: sum the 8 K-chunk partials ----------------
__global__ __launch_bounds__(256) void k_Cred(const float* __restrict__ part,
                                              float* __restrict__ out) {
  const int row = blockIdx.x;   // 0..1023
  const int d   = threadIdx.x;
  float s = 0.f;
  #pragma unroll
  for (int kc = 0; kc < 8; ++kc)
    s += part[((size_t)kc << 18) + row * D256 + d];
  out[row * D256 + d] = s;
}

extern "C" void kernel_launch(void* const* d_in, const int* in_sizes, int n_in,
                              void* d_out, int out_size, void* d_ws, size_t ws_size,
                              hipStream_t stream) {
  const float* x       = (const float*)d_in[0];
  const float* M       = (const float*)d_in[1];
  const float* P       = (const float*)d_in[2];
  const float* Linker  = (const float*)d_in[3];
  const float* gamma   = (const float*)d_in[4];
  const float* beta    = (const float*)d_in[5];
  const float* resW    = (const float*)d_in[6];
  const float* rLinker = (const float*)d_in[7];
  float* out = (float*)d_out;

  char* ws = (char*)d_ws;
  float4*         PIt4   = (float4*)(ws);                           // 1 MB
  unsigned short* LinkTb = (unsigned short*)(ws + 1024 * 1024);     // 2 MB
  unsigned short* Bt     = (unsigned short*)(ws + 3072 * 1024);     // 2 MB
  unsigned short* xb     = (unsigned short*)(ws + 5120 * 1024);     // 1 MB
  unsigned short* Mb     = (unsigned short*)(ws + 6144 * 1024);     // 128 KB
  unsigned short* Wb     = (unsigned short*)(ws + 6272 * 1024);     // 128 KB
  float*          Zb     = (float*)(ws + 6400 * 1024);              // 2 MB
  float*          part   = (float*)(ws + 8448 * 1024);              // 8 MB

  hipLaunchKernelGGL(k_prep, dim3(832),  dim3(256), 0, stream,
                     x, M, resW, P, Linker, rLinker, PIt4, LinkTb, xb, Mb, Wb);
  hipLaunchKernelGGL(k_Azn,  dim3(128),  dim3(256), 0, stream,
                     xb, Mb, Wb, gamma, beta, Zb, Bt);
  hipLaunchKernelGGL(k_B,    dim3(4096), dim3(256), 0, stream, Zb, PIt4, Bt);
  hipLaunchKernelGGL(k_Cm,   dim3(512),  dim3(256), 0, stream, LinkTb, Bt, part);
  hipLaunchKernelGGL(k_Cred, dim3(1024), dim3(256), 0, stream, part, out);
}